// Round 1
// baseline (7231.142 us; speedup 1.0000x reference)
//
#include <hip/hip_runtime.h>
#include <hip/hip_bf16.h>

#define VOCAB 32000
#define EMB   128
#define HID   256
#define G4H   1024
#define BS    8
#define SEQ   1024
#define NWG   8

typedef __attribute__((ext_vector_type(8))) short short8;
typedef __attribute__((ext_vector_type(4))) float f32x4;

static __device__ __forceinline__ unsigned short f2bf(float x) {
  union { __hip_bfloat16 b; unsigned short u; } cv;
  cv.b = __float2bfloat16(x);
  return cv.u;
}
static __device__ __forceinline__ float bf2f(unsigned short u) {
  union { unsigned short u; __hip_bfloat16 b; } cv;
  cv.u = u;
  return __bfloat162float(cv.b);
}

// ---------------- Kernel 1: embedding gather + x@W + bias -> xW (f32, in d_out scratch)
__global__ __launch_bounds__(256) void k_embed_xw(
    const int* __restrict__ sent, const float* __restrict__ wemb,
    const float* __restrict__ W, const float* __restrict__ bias,
    float* __restrict__ xW) {
  int tid = threadIdx.x;
  int blk = blockIdx.x;          // 2048 blocks
  int b  = blk >> 8;
  int t0 = (blk & 255) << 2;     // 4 timesteps per block
  __shared__ float xs[4][EMB];
  #pragma unroll
  for (int i = 0; i < 2; ++i) {
    int flat = tid + (i << 8);
    int r = flat >> 7, e = flat & 127;
    int idx = sent[b * SEQ + t0 + r];
    xs[r][e] = wemb[idx * EMB + e];
  }
  __syncthreads();
  int g0 = tid << 2;
  float acc[4][4] = {};
  for (int e = 0; e < EMB; ++e) {
    float4 w4 = *(const float4*)&W[e * G4H + g0];
    #pragma unroll
    for (int r = 0; r < 4; ++r) {
      float xv = xs[r][e];
      acc[r][0] += xv * w4.x; acc[r][1] += xv * w4.y;
      acc[r][2] += xv * w4.z; acc[r][3] += xv * w4.w;
    }
  }
  float4 bi = *(const float4*)&bias[g0];
  #pragma unroll
  for (int r = 0; r < 4; ++r) {
    float4 o;
    o.x = acc[r][0] + bi.x; o.y = acc[r][1] + bi.y;
    o.z = acc[r][2] + bi.z; o.w = acc[r][3] + bi.w;
    *(float4*)&xW[(size_t)(b * SEQ + t0 + r) * G4H + g0] = o;
  }
}

// ---------------- Kernel 2: w_linear (256 x 32000 f32) -> BT (32000 x 256 bf16)
__global__ __launch_bounds__(256) void k_transpose_w(
    const float* __restrict__ w, unsigned short* __restrict__ BT) {
  __shared__ unsigned short tile[64][66];
  int n0 = blockIdx.x * 64, k0 = blockIdx.y * 64;
  int tid = threadIdx.x;
  #pragma unroll
  for (int i = 0; i < 16; ++i) {
    int flat = tid + i * 256;
    int kk = flat >> 6, nn = flat & 63;
    tile[kk][nn] = f2bf(w[(size_t)(k0 + kk) * VOCAB + n0 + nn]);
  }
  __syncthreads();
  #pragma unroll
  for (int i = 0; i < 16; ++i) {
    int flat = tid + i * 256;
    int nn = flat >> 6, kk = flat & 63;
    BT[(size_t)(n0 + nn) * HID + k0 + kk] = tile[kk][nn];
  }
}

// ---------------- Kernel 3: persistent LSTM scan
// 8 WGs x 512 threads. WG w owns hidden units [w*32, w*32+32).
// U slice as split-bf16 MFMA B-fragments in registers. h exchanged through a
// global A-pack buffer (MFMA A-fragment layout, double-buffered), flag barrier.
__global__ __launch_bounds__(512) void k_scan(
    const float* __restrict__ xW, const float* __restrict__ U,
    unsigned short* __restrict__ hidden,   // [8192][256] bf16
    unsigned short* __restrict__ apack,    // [2 buf][2 hi/lo][32 kq][16 r][8 j]
    int* __restrict__ flags) {
  const int w = blockIdx.x;
  const int tid = threadIdx.x;
  const int l = tid & 63, v = tid >> 6;

  // Zero pad rows r=8..15 of both A-pack buffers (read as zeros by MFMA forever).
  if (w == 0) {
    for (int idx = tid; idx < 2 * 2 * 32 * 8 * 8; idx += 512) {
      int j   = idx & 7;
      int r8  = (idx >> 3) & 7;
      int kq  = (idx >> 6) & 31;
      int arr = (idx >> 11) & 3;   // buf*2 + hilo
      apack[arr * (32 * 16 * 8) + (kq * 16 + 8 + r8) * 8 + j] = 0;
    }
  }

  // Load persistent U B-fragments (split bf16 hi/lo).
  const int g = v >> 1, half = v & 1;
  const int col = g * HID + w * 32 + half * 16 + (l & 15);
  short8 bhi[8], blo[8];
  #pragma unroll
  for (int kb = 0; kb < 8; ++kb) {
    #pragma unroll
    for (int j = 0; j < 8; ++j) {
      int k = kb * 32 + (l >> 4) * 8 + j;
      float uv = U[k * G4H + col];
      unsigned short h16 = f2bf(uv);
      bhi[kb][j] = (short)h16;
      blo[kb][j] = (short)f2bf(uv - bf2f(h16));
    }
  }

  __shared__ float gl[8 * 128];   // [batch][local gate col]

  float c = 0.f;
  const int b = tid >> 5, ul = tid & 31;  // update mapping (tid < 256)

  for (int t = 0; t < SEQ; ++t) {
    // prefetch xW for this step (independent of barrier)
    float xw[4];
    if (tid < 256) {
      #pragma unroll
      for (int gg = 0; gg < 4; ++gg)
        xw[gg] = xW[(size_t)(b * SEQ + t) * G4H + gg * HID + w * 32 + ul];
    }

    if (t > 0) {
      if (tid < NWG) {
        int guard = 0;
        while (__hip_atomic_load(&flags[tid], __ATOMIC_ACQUIRE,
                                 __HIP_MEMORY_SCOPE_AGENT) < t) {
          if (++guard > 3000000) break;   // anti-deadlock bailout
        }
      }
      __syncthreads();
      const unsigned short* ahi_p = apack + ((t - 1) & 1) * (2 * 32 * 16 * 8);
      const unsigned short* alo_p = ahi_p + 32 * 16 * 8;
      f32x4 acc = {0.f, 0.f, 0.f, 0.f};
      #pragma unroll
      for (int kb = 0; kb < 8; ++kb) {
        int off = ((kb * 4 + (l >> 4)) * 16 + (l & 15)) * 8;
        short8 ahi = *(const short8*)(ahi_p + off);
        short8 alo = *(const short8*)(alo_p + off);
        acc = __builtin_amdgcn_mfma_f32_16x16x32_bf16(ahi, bhi[kb], acc, 0, 0, 0);
        acc = __builtin_amdgcn_mfma_f32_16x16x32_bf16(ahi, blo[kb], acc, 0, 0, 0);
        acc = __builtin_amdgcn_mfma_f32_16x16x32_bf16(alo, bhi[kb], acc, 0, 0, 0);
      }
      if (l < 32) {
        int lc = v * 16 + (l & 15);
        #pragma unroll
        for (int q = 0; q < 4; ++q)
          gl[((l >> 4) * 4 + q) * 128 + lc] = acc[q];
      }
    }
    __syncthreads();

    if (tid < 256) {
      float gv[4];
      #pragma unroll
      for (int gg = 0; gg < 4; ++gg) {
        float s = (t > 0) ? gl[b * 128 + gg * 32 + ul] : 0.f;
        gv[gg] = s + xw[gg];
      }
      float iv = 1.f / (1.f + expf(-gv[0]));
      float fv = 1.f / (1.f + expf(-gv[1]));
      float gg2 = tanhf(gv[2]);
      float ov = 1.f / (1.f + expf(-gv[3]));
      c = fv * c + iv * gg2;
      float h = ov * tanhf(c);
      unsigned short hhi = f2bf(h);
      hidden[(size_t)(b * SEQ + t) * HID + w * 32 + ul] = hhi;
      float hlo = h - bf2f(hhi);
      unsigned short* apw = apack + (t & 1) * (2 * 32 * 16 * 8);
      int kq = w * 4 + (ul >> 3), j = ul & 7;
      apw[(kq * 16 + b) * 8 + j] = hhi;
      apw[32 * 16 * 8 + (kq * 16 + b) * 8 + j] = f2bf(hlo);
    }
    __threadfence();
    __syncthreads();
    if (tid == 0)
      __hip_atomic_store(&flags[w], t + 1, __ATOMIC_RELEASE,
                         __HIP_MEMORY_SCOPE_AGENT);
  }
}

// ---------------- Kernel 4: hidden @ w_linear^T + bias -> out (bf16 MFMA, f32 out)
__global__ __launch_bounds__(256) void k_gemm_out(
    const unsigned short* __restrict__ A,   // [8192][256] bf16
    const unsigned short* __restrict__ BT,  // [32000][256] bf16
    const float* __restrict__ bias, float* __restrict__ C) {
  const int n0 = blockIdx.x * 128;
  const int m0 = blockIdx.y * 128;
  const int tid = threadIdx.x;
  const int l = tid & 63, wv = tid >> 6;
  const int wr = wv >> 1, wc = wv & 1;
  __shared__ unsigned short As[128 * 72];
  __shared__ unsigned short Bs[128 * 72];
  f32x4 acc[4][4] = {};
  const int r = tid >> 1, seg = tid & 1;
  for (int kt = 0; kt < 4; ++kt) {
    int k0 = kt * 64;
    #pragma unroll
    for (int i = 0; i < 4; ++i) {
      *(short8*)&As[r * 72 + seg * 32 + i * 8] =
          *(const short8*)&A[(size_t)(m0 + r) * HID + k0 + seg * 32 + i * 8];
      *(short8*)&Bs[r * 72 + seg * 32 + i * 8] =
          *(const short8*)&BT[(size_t)(n0 + r) * HID + k0 + seg * 32 + i * 8];
    }
    __syncthreads();
    #pragma unroll
    for (int kb = 0; kb < 2; ++kb) {
      short8 af[4], bf[4];
      #pragma unroll
      for (int mi = 0; mi < 4; ++mi)
        af[mi] = *(const short8*)&As[(wr * 64 + mi * 16 + (l & 15)) * 72 +
                                     kb * 32 + (l >> 4) * 8];
      #pragma unroll
      for (int ni = 0; ni < 4; ++ni)
        bf[ni] = *(const short8*)&Bs[(wc * 64 + ni * 16 + (l & 15)) * 72 +
                                     kb * 32 + (l >> 4) * 8];
      #pragma unroll
      for (int mi = 0; mi < 4; ++mi)
        #pragma unroll
        for (int ni = 0; ni < 4; ++ni)
          acc[mi][ni] = __builtin_amdgcn_mfma_f32_16x16x32_bf16(
              af[mi], bf[ni], acc[mi][ni], 0, 0, 0);
    }
    __syncthreads();
  }
  #pragma unroll
  for (int ni = 0; ni < 4; ++ni) {
    int n = n0 + wc * 64 + ni * 16 + (l & 15);
    float bi = bias[n];
    #pragma unroll
    for (int mi = 0; mi < 4; ++mi) {
      int mbase = m0 + wr * 64 + mi * 16 + (l >> 4) * 4;
      #pragma unroll
      for (int q = 0; q < 4; ++q)
        C[(size_t)(mbase + q) * VOCAB + n] = acc[mi][ni][q] + bi;
    }
  }
}

extern "C" void kernel_launch(void* const* d_in, const int* in_sizes, int n_in,
                              void* d_out, int out_size, void* d_ws, size_t ws_size,
                              hipStream_t stream) {
  const int*   sent = (const int*)d_in[0];
  const float* wemb = (const float*)d_in[1];
  const float* W    = (const float*)d_in[2];
  const float* U    = (const float*)d_in[3];
  const float* bias = (const float*)d_in[4];
  const float* wlin = (const float*)d_in[5];
  const float* blin = (const float*)d_in[6];
  float* out = (float*)d_out;

  // xW (32 MB f32) lives in d_out scratch; GEMM overwrites all of d_out later.
  float* xW = out;

  char* ws = (char*)d_ws;
  unsigned short* BT     = (unsigned short*)ws;                    // 16,384,000 B
  unsigned short* hidden = (unsigned short*)(ws + 16384000);       //  4,194,304 B
  unsigned short* apack  = (unsigned short*)(ws + 16384000 + 4194304); // 32,768 B
  int* flags = (int*)(ws + 16384000 + 4194304 + 32768);            // 32 B

  hipMemsetAsync(flags, 0, NWG * sizeof(int), stream);
  k_embed_xw<<<2048, 256, 0, stream>>>(sent, wemb, W, bias, xW);
  k_transpose_w<<<dim3(500, 4), 256, 0, stream>>>(wlin, BT);
  k_scan<<<NWG, 512, 0, stream>>>(xW, U, hidden, apack, flags);
  k_gemm_out<<<dim3(250, 64), 256, 0, stream>>>(hidden, BT, blin, out);
}

// Round 2
// 3631.293 us; speedup vs baseline: 1.9913x; 1.9913x over previous
//
#include <hip/hip_runtime.h>
#include <hip/hip_bf16.h>

#define VOCAB 32000
#define EMB   128
#define HID   256
#define G4H   1024
#define BS    8
#define SEQ   1024
#define NWG   8

typedef __attribute__((ext_vector_type(8))) short short8;
typedef __attribute__((ext_vector_type(4))) float f32x4;

static __device__ __forceinline__ unsigned short f2bf(float x) {
  union { __hip_bfloat16 b; unsigned short u; } cv;
  cv.b = __float2bfloat16(x);
  return cv.u;
}
static __device__ __forceinline__ float bf2f(unsigned short u) {
  union { unsigned short u; __hip_bfloat16 b; } cv;
  cv.u = u;
  return __bfloat162float(cv.b);
}

// ---- LLC-direct (coherence-point) accesses: bypass L1+L2, no cache maintenance.
static __device__ __forceinline__ void st_short_cc(unsigned short* p, unsigned int v) {
  asm volatile("global_store_short %0, %1, off sc0 sc1" :: "v"(p), "v"(v) : "memory");
}
static __device__ __forceinline__ void st_int_cc(int* p, int v) {
  asm volatile("global_store_dword %0, %1, off sc0 sc1" :: "v"(p), "v"(v) : "memory");
}
static __device__ __forceinline__ int ld_int_cc(const int* p) {
  int r;
  asm volatile("global_load_dword %0, %1, off sc0 sc1\n\ts_waitcnt vmcnt(0)"
               : "=v"(r) : "v"(p) : "memory");
  return r;
}
static __device__ __forceinline__ short8 ld16_cc(const unsigned short* p) {
  short8 r;
  asm volatile("global_load_dwordx4 %0, %1, off sc0 sc1" : "=v"(r) : "v"(p) : "memory");
  return r;
}

static __device__ __forceinline__ float fsigmoid(float x) {
  return 1.f / (1.f + __expf(-x));
}
static __device__ __forceinline__ float ftanh(float x) {
  return 2.f / (1.f + __expf(-2.f * x)) - 1.f;
}

// ---------------- Kernel 1: embedding gather + x@W + bias -> xW (f32, in d_out scratch)
__global__ __launch_bounds__(256) void k_embed_xw(
    const int* __restrict__ sent, const float* __restrict__ wemb,
    const float* __restrict__ W, const float* __restrict__ bias,
    float* __restrict__ xW) {
  int tid = threadIdx.x;
  int blk = blockIdx.x;          // 2048 blocks
  int b  = blk >> 8;
  int t0 = (blk & 255) << 2;     // 4 timesteps per block
  __shared__ float xs[4][EMB];
  #pragma unroll
  for (int i = 0; i < 2; ++i) {
    int flat = tid + (i << 8);
    int r = flat >> 7, e = flat & 127;
    int idx = sent[b * SEQ + t0 + r];
    xs[r][e] = wemb[idx * EMB + e];
  }
  __syncthreads();
  int g0 = tid << 2;
  float acc[4][4] = {};
  for (int e = 0; e < EMB; ++e) {
    float4 w4 = *(const float4*)&W[e * G4H + g0];
    #pragma unroll
    for (int r = 0; r < 4; ++r) {
      float xv = xs[r][e];
      acc[r][0] += xv * w4.x; acc[r][1] += xv * w4.y;
      acc[r][2] += xv * w4.z; acc[r][3] += xv * w4.w;
    }
  }
  float4 bi = *(const float4*)&bias[g0];
  #pragma unroll
  for (int r = 0; r < 4; ++r) {
    float4 o;
    o.x = acc[r][0] + bi.x; o.y = acc[r][1] + bi.y;
    o.z = acc[r][2] + bi.z; o.w = acc[r][3] + bi.w;
    *(float4*)&xW[(size_t)(b * SEQ + t0 + r) * G4H + g0] = o;
  }
}

// ---------------- Kernel 2: w_linear (256 x 32000 f32) -> BT (32000 x 256 bf16)
__global__ __launch_bounds__(256) void k_transpose_w(
    const float* __restrict__ w, unsigned short* __restrict__ BT) {
  __shared__ unsigned short tile[64][66];
  int n0 = blockIdx.x * 64, k0 = blockIdx.y * 64;
  int tid = threadIdx.x;
  #pragma unroll
  for (int i = 0; i < 16; ++i) {
    int flat = tid + i * 256;
    int kk = flat >> 6, nn = flat & 63;
    tile[kk][nn] = f2bf(w[(size_t)(k0 + kk) * VOCAB + n0 + nn]);
  }
  __syncthreads();
  #pragma unroll
  for (int i = 0; i < 16; ++i) {
    int flat = tid + i * 256;
    int nn = flat >> 6, kk = flat & 63;
    BT[(size_t)(n0 + nn) * HID + k0 + kk] = tile[kk][nn];
  }
}

// ---------------- Kernel 3: persistent LSTM scan
// 8 WGs x 512 threads. WG w owns hidden units [w*32, w*32+32).
// U slice as split-bf16 MFMA B-fragments in registers. h exchanged through a
// global A-pack buffer (MFMA A-fragment layout, double-buffered).
// All inter-WG state (apack, flags) moves via sc0|sc1 LLC-direct ops; ordering
// by per-wave s_waitcnt vmcnt(0) + __syncthreads. No buffer_inv/wbl2 anywhere.
__global__ __launch_bounds__(512) void k_scan(
    const float* __restrict__ xW, const float* __restrict__ U,
    unsigned short* __restrict__ hidden,   // [8192][256] bf16
    unsigned short* __restrict__ apack,    // [2 buf][2 hi/lo][32 kq][16 r][8 j]
    int* __restrict__ flags) {
  const int w = blockIdx.x;
  const int tid = threadIdx.x;
  const int l = tid & 63, v = tid >> 6;

  // Zero pad rows r=8..15 of both A-pack buffers (LLC-direct so readers see it).
  if (w == 0) {
    for (int idx = tid; idx < 2 * 2 * 32 * 8 * 8; idx += 512) {
      int j   = idx & 7;
      int r8  = (idx >> 3) & 7;
      int kq  = (idx >> 6) & 31;
      int arr = (idx >> 11) & 3;   // buf*2 + hilo
      st_short_cc(&apack[arr * (32 * 16 * 8) + (kq * 16 + 8 + r8) * 8 + j], 0u);
    }
  }

  // Load persistent U B-fragments (split bf16 hi/lo).
  const int g = v >> 1, half = v & 1;
  const int col = g * HID + w * 32 + half * 16 + (l & 15);
  short8 bhi[8], blo[8];
  #pragma unroll
  for (int kb = 0; kb < 8; ++kb) {
    #pragma unroll
    for (int j = 0; j < 8; ++j) {
      int k = kb * 32 + (l >> 4) * 8 + j;
      float uv = U[k * G4H + col];
      unsigned short h16 = f2bf(uv);
      bhi[kb][j] = (short)h16;
      blo[kb][j] = (short)f2bf(uv - bf2f(h16));
    }
  }

  __shared__ float gl[8 * 128];   // [batch][local gate col]

  float c = 0.f;
  const int b = tid >> 5, ul = tid & 31;  // update mapping (tid < 256)

  for (int t = 0; t < SEQ; ++t) {
    // prefetch xW for this step (independent of the flag wait)
    float xw[4];
    if (tid < 256) {
      #pragma unroll
      for (int gg = 0; gg < 4; ++gg)
        xw[gg] = xW[(size_t)(b * SEQ + t) * G4H + gg * HID + w * 32 + ul];
    }

    if (t > 0) {
      if (tid < NWG) {
        int guard = 0;
        while (ld_int_cc(&flags[tid]) < t) {
          if (++guard > 3000000) break;   // anti-deadlock bailout
        }
      }
      __syncthreads();
      const unsigned short* ahi_p = apack + ((t - 1) & 1) * (2 * 32 * 16 * 8);
      const unsigned short* alo_p = ahi_p + 32 * 16 * 8;
      short8 ahf[8], alf[8];
      #pragma unroll
      for (int kb = 0; kb < 8; ++kb) {
        int off = ((kb * 4 + (l >> 4)) * 16 + (l & 15)) * 8;
        ahf[kb] = ld16_cc(ahi_p + off);
        alf[kb] = ld16_cc(alo_p + off);
      }
      asm volatile("s_waitcnt vmcnt(0)" ::: "memory");
      __builtin_amdgcn_sched_barrier(0);
      f32x4 acc = {0.f, 0.f, 0.f, 0.f};
      #pragma unroll
      for (int kb = 0; kb < 8; ++kb) {
        acc = __builtin_amdgcn_mfma_f32_16x16x32_bf16(ahf[kb], bhi[kb], acc, 0, 0, 0);
        acc = __builtin_amdgcn_mfma_f32_16x16x32_bf16(ahf[kb], blo[kb], acc, 0, 0, 0);
        acc = __builtin_amdgcn_mfma_f32_16x16x32_bf16(alf[kb], bhi[kb], acc, 0, 0, 0);
      }
      if (l < 32) {
        int lc = v * 16 + (l & 15);
        #pragma unroll
        for (int q = 0; q < 4; ++q)
          gl[((l >> 4) * 4 + q) * 128 + lc] = acc[q];
      }
    }
    __syncthreads();

    if (tid < 256) {
      float gv[4];
      #pragma unroll
      for (int gg = 0; gg < 4; ++gg) {
        float s = (t > 0) ? gl[b * 128 + gg * 32 + ul] : 0.f;
        gv[gg] = s + xw[gg];
      }
      float iv = fsigmoid(gv[0]);
      float fv = fsigmoid(gv[1]);
      float gg2 = ftanh(gv[2]);
      float ov = fsigmoid(gv[3]);
      c = fv * c + iv * gg2;
      float h = ov * ftanh(c);
      unsigned short hhi = f2bf(h);
      hidden[(size_t)(b * SEQ + t) * HID + w * 32 + ul] = hhi;   // plain (cached) ok
      float hlo = h - bf2f(hhi);
      unsigned short* apw = apack + (t & 1) * (2 * 32 * 16 * 8);
      int kq = w * 4 + (ul >> 3), j = ul & 7;
      st_short_cc(&apw[(kq * 16 + b) * 8 + j], (unsigned)hhi);
      st_short_cc(&apw[32 * 16 * 8 + (kq * 16 + b) * 8 + j], (unsigned)f2bf(hlo));
    }
    // Per-wave drain: every wave's outstanding stores (incl. pad init at t=0)
    // are LLC-acknowledged before the barrier; flag store is ordered after.
    asm volatile("s_waitcnt vmcnt(0)" ::: "memory");
    __syncthreads();
    if (tid == 0) st_int_cc(&flags[w], t + 1);
  }
}

// ---------------- Kernel 4: hidden @ w_linear^T + bias -> out (bf16 MFMA, f32 out)
__global__ __launch_bounds__(256) void k_gemm_out(
    const unsigned short* __restrict__ A,   // [8192][256] bf16
    const unsigned short* __restrict__ BT,  // [32000][256] bf16
    const float* __restrict__ bias, float* __restrict__ C) {
  const int n0 = blockIdx.x * 128;
  const int m0 = blockIdx.y * 128;
  const int tid = threadIdx.x;
  const int l = tid & 63, wv = tid >> 6;
  const int wr = wv >> 1, wc = wv & 1;
  __shared__ unsigned short As[128 * 72];
  __shared__ unsigned short Bs[128 * 72];
  f32x4 acc[4][4] = {};
  const int r = tid >> 1, seg = tid & 1;
  for (int kt = 0; kt < 4; ++kt) {
    int k0 = kt * 64;
    #pragma unroll
    for (int i = 0; i < 4; ++i) {
      *(short8*)&As[r * 72 + seg * 32 + i * 8] =
          *(const short8*)&A[(size_t)(m0 + r) * HID + k0 + seg * 32 + i * 8];
      *(short8*)&Bs[r * 72 + seg * 32 + i * 8] =
          *(const short8*)&BT[(size_t)(n0 + r) * HID + k0 + seg * 32 + i * 8];
    }
    __syncthreads();
    #pragma unroll
    for (int kb = 0; kb < 2; ++kb) {
      short8 af[4], bf[4];
      #pragma unroll
      for (int mi = 0; mi < 4; ++mi)
        af[mi] = *(const short8*)&As[(wr * 64 + mi * 16 + (l & 15)) * 72 +
                                     kb * 32 + (l >> 4) * 8];
      #pragma unroll
      for (int ni = 0; ni < 4; ++ni)
        bf[ni] = *(const short8*)&Bs[(wc * 64 + ni * 16 + (l & 15)) * 72 +
                                     kb * 32 + (l >> 4) * 8];
      #pragma unroll
      for (int mi = 0; mi < 4; ++mi)
        #pragma unroll
        for (int ni = 0; ni < 4; ++ni)
          acc[mi][ni] = __builtin_amdgcn_mfma_f32_16x16x32_bf16(
              af[mi], bf[ni], acc[mi][ni], 0, 0, 0);
    }
    __syncthreads();
  }
  #pragma unroll
  for (int ni = 0; ni < 4; ++ni) {
    int n = n0 + wc * 64 + ni * 16 + (l & 15);
    float bi = bias[n];
    #pragma unroll
    for (int mi = 0; mi < 4; ++mi) {
      int mbase = m0 + wr * 64 + mi * 16 + (l >> 4) * 4;
      #pragma unroll
      for (int q = 0; q < 4; ++q)
        C[(size_t)(mbase + q) * VOCAB + n] = acc[mi][ni][q] + bi;
    }
  }
}

extern "C" void kernel_launch(void* const* d_in, const int* in_sizes, int n_in,
                              void* d_out, int out_size, void* d_ws, size_t ws_size,
                              hipStream_t stream) {
  const int*   sent = (const int*)d_in[0];
  const float* wemb = (const float*)d_in[1];
  const float* W    = (const float*)d_in[2];
  const float* U    = (const float*)d_in[3];
  const float* bias = (const float*)d_in[4];
  const float* wlin = (const float*)d_in[5];
  const float* blin = (const float*)d_in[6];
  float* out = (float*)d_out;

  // xW (32 MB f32) lives in d_out scratch; GEMM overwrites all of d_out later.
  float* xW = out;

  char* ws = (char*)d_ws;
  unsigned short* BT     = (unsigned short*)ws;                    // 16,384,000 B
  unsigned short* hidden = (unsigned short*)(ws + 16384000);       //  4,194,304 B
  unsigned short* apack  = (unsigned short*)(ws + 16384000 + 4194304); // 32,768 B
  int* flags = (int*)(ws + 16384000 + 4194304 + 32768);            // 32 B

  hipMemsetAsync(flags, 0, NWG * sizeof(int), stream);
  k_embed_xw<<<2048, 256, 0, stream>>>(sent, wemb, W, bias, xW);
  k_transpose_w<<<dim3(500, 4), 256, 0, stream>>>(wlin, BT);
  k_scan<<<NWG, 512, 0, stream>>>(xW, U, hidden, apack, flags);
  k_gemm_out<<<dim3(250, 64), 256, 0, stream>>>(hidden, BT, blin, out);
}